// Round 1
// baseline (498.514 us; speedup 1.0000x reference)
//
#include <hip/hip_runtime.h>
#include <cstdint>
#include <cstddef>

// Problem constants
#define D_DIM 64
#define M_DIM 256
#define N_PTS 1024

static __device__ __forceinline__ float sp10f(float x) {
    // softplus(10x)/10, numerically stable, matches jax.nn.softplus
    float t = 10.f * x;
    return 0.1f * (fmaxf(t, 0.f) + log1pf(__expf(-fabsf(t))));
}

static __device__ __forceinline__ float ftanh(float x) {
    float ax = fminf(fabsf(x), 15.f);
    float e  = __expf(2.f * ax);
    float t  = 1.f - 2.f * __builtin_amdgcn_rcpf(e + 1.f);
    return copysignf(t, x);
}

// ---------------- prep: transform weights (n-independent) ----------------
__global__ void k_prep_w(const float* __restrict__ wf, const float* __restrict__ wm,
                         const float* __restrict__ wl, const float* __restrict__ af,
                         const float* __restrict__ am,
                         float* __restrict__ W1t, float* __restrict__ Wmt,
                         float* __restrict__ Wlt, float* __restrict__ Ta1,
                         float* __restrict__ Tam) {
    const int S0 = 49152, S1 = 294912, S2 = 49152, S3 = 49152, S4 = 98304;
    const int total = S0 + S1 + S2 + S3 + S4;
    for (int i = blockIdx.x * blockDim.x + threadIdx.x; i < total;
         i += gridDim.x * blockDim.x) {
        int j = i;
        if (j < S0) { W1t[j] = sp10f(wf[j]); continue; }
        j -= S0;
        if (j < S1) { Wmt[j] = sp10f(wm[j]); continue; }
        j -= S1;
        if (j < S2) { Wlt[j] = sp10f(wl[j]); continue; }
        j -= S2;
        if (j < S3) { Ta1[j] = tanhf(af[j]); continue; }
        j -= S3;
        Tam[j] = tanhf(am[j]);
    }
}

// map global level-group index g (0..61) -> (raw pointer, local g)
static __device__ __forceinline__ const float* map_g(int g, const float* a0, const float* a1,
                                                     const float* a2, const float* a3,
                                                     const float* a4, int& lg) {
    if (g < 32) { lg = g;      return a0; }
    if (g < 48) { lg = g - 32; return a1; }
    if (g < 56) { lg = g - 48; return a2; }
    if (g < 60) { lg = g - 56; return a3; }
    lg = g - 60; return a4;
}

// column sums of sp10(A) over m (axis=1). One block per g, threads = k.
__global__ void k_csum(const float* __restrict__ a0, const float* __restrict__ a1,
                       const float* __restrict__ a2, const float* __restrict__ a3,
                       const float* __restrict__ a4, float* __restrict__ csum) {
    int g = blockIdx.x;   // 0..61
    int k = threadIdx.x;  // 0..255
    int lg;
    const float* A = map_g(g, a0, a1, a2, a3, a4, lg);
    const float* base = A + (size_t)lg * 65536 + k;
    float s = 0.f;
    for (int m = 0; m < 256; m++) s += sp10f(base[(size_t)m * 256]);
    csum[g * 256 + k] = s;
}

// normalized A: An[g][m][k] = sp10(raw)/csum[g][k]
__global__ void k_anorm(const float* __restrict__ a0, const float* __restrict__ a1,
                        const float* __restrict__ a2, const float* __restrict__ a3,
                        const float* __restrict__ a4, const float* __restrict__ csum,
                        float* __restrict__ An) {
    const int total = 62 * 65536;
    for (int i = blockIdx.x * blockDim.x + threadIdx.x; i < total;
         i += gridDim.x * blockDim.x) {
        int g = i >> 16;
        int r = i & 65535;
        int lg;
        const float* A = map_g(g, a0, a1, a2, a3, a4, lg);
        float v = sp10f(A[(size_t)lg * 65536 + r]);
        An[i] = v / csum[(g << 8) | (r & 255)];
    }
}

// ---------------- phase 1: per-(n,d,m) MLP chains, fused d-pair product ---
// grid: (j=0..31, nc=0..31), block 256 threads = m. Output P0[j][n][m].
__global__ __launch_bounds__(256, 3) void k_phase1(
    const float* __restrict__ X, const float* __restrict__ W1t,
    const float* __restrict__ Wmt, const float* __restrict__ Wlt,
    const float* __restrict__ b1, const float* __restrict__ bm,
    const float* __restrict__ bl, const float* __restrict__ Ta1,
    const float* __restrict__ Tam, float* __restrict__ P0) {
    const int m  = threadIdx.x;
    const int j  = blockIdx.x;  // d-pair
    const int nc = blockIdx.y;  // n-chunk (32 n each)
    const int d0 = 2 * j;

    float W1[2][3], Wm[2][2][9], Wl[2][3], B1[2][3], Bm[2][2][3], Bl[2], T1[2][3], Tm[2][2][3];
#pragma unroll
    for (int e = 0; e < 2; e++) {
        const int d  = d0 + e;
        const int dm = d * M_DIM + m;
#pragma unroll
        for (int r = 0; r < 3; r++) {
            W1[e][r] = W1t[dm * 3 + r];
            B1[e][r] = b1[dm * 3 + r];
            T1[e][r] = Ta1[dm * 3 + r];
            Wl[e][r] = Wlt[dm * 3 + r];
        }
        Bl[e] = bl[dm];
#pragma unroll
        for (int l = 0; l < 2; l++) {
            const size_t b9 = ((size_t)(l * D_DIM + d) * M_DIM + m) * 9;
            const size_t b3 = ((size_t)(l * D_DIM + d) * M_DIM + m) * 3;
#pragma unroll
            for (int q = 0; q < 9; q++) Wm[e][l][q] = Wmt[b9 + q];
#pragma unroll
            for (int r = 0; r < 3; r++) {
                Bm[e][l][r] = bm[b3 + r];
                Tm[e][l][r] = Tam[b3 + r];
            }
        }
    }

    float* outp = P0 + ((size_t)j * N_PTS + nc * 32) * M_DIM + m;
    for (int ni = 0; ni < 32; ni++) {
        const int n = nc * 32 + ni;
        float prod[2];
#pragma unroll
        for (int e = 0; e < 2; e++) {
            const float x = X[n * D_DIM + d0 + e];
            float phi[3], pd[3];
#pragma unroll
            for (int r = 0; r < 3; r++) {
                float z  = fmaf(x, W1[e][r], B1[e][r]);
                float tz = ftanh(z);
                float ta = T1[e][r];
                pd[r]  = W1[e][r] * (1.f + ta * (1.f - tz * tz));
                phi[r] = z + tz * ta;
            }
#pragma unroll
            for (int l = 0; l < 2; l++) {
                float nphi[3], npd[3];
#pragma unroll
                for (int q = 0; q < 3; q++) {
                    float z = Bm[e][l][q];
                    float dp = 0.f;
#pragma unroll
                    for (int r = 0; r < 3; r++) {
                        z  = fmaf(phi[r], Wm[e][l][r * 3 + q], z);
                        dp = fmaf(pd[r],  Wm[e][l][r * 3 + q], dp);
                    }
                    float tz = ftanh(z);
                    float ta = Tm[e][l][q];
                    nphi[q] = z + tz * ta;
                    npd[q]  = dp * (1.f + ta * (1.f - tz * tz));
                }
#pragma unroll
                for (int q = 0; q < 3; q++) { phi[q] = nphi[q]; pd[q] = npd[q]; }
            }
            float z = Bl[e], dp = 0.f;
#pragma unroll
            for (int r = 0; r < 3; r++) {
                z  = fmaf(phi[r], Wl[e][r], z);
                dp = fmaf(pd[r],  Wl[e][r], dp);
            }
            float s = __builtin_amdgcn_rcpf(1.f + __expf(-z));
            prod[e] = dp * s * (1.f - s);
        }
        outp[(size_t)ni * M_DIM] = prod[0] * prod[1];
    }
}

// ---------------- phase 2: batched fp32 GEMM -----------------------------
// out[g][n][k] = sum_m in(g-or-pair)[n][m] * An[g][m][k]
// tile 128x128, KC=32, 256 threads, 8x8 micro-tile (split 4+4).
#define BMT 128
#define BNT 128
#define KCT 32

template <int PAIRED>
__global__ __launch_bounds__(256, 2) void k_gemm(const float* __restrict__ Tin,
                                                 const float* __restrict__ An,
                                                 float* __restrict__ Tout) {
    __shared__ float sA[KCT][BMT + 4];
    __shared__ float sB[KCT][BNT + 4];

    const int g  = blockIdx.z;
    const int n0 = blockIdx.x * BMT;
    const int k0 = blockIdx.y * BNT;
    const float* Ag = An + (size_t)g * 65536;
    const float* T0;
    const float* T1p = nullptr;
    if (PAIRED) {
        T0  = Tin + (size_t)(2 * g) * N_PTS * 256;
        T1p = T0 + (size_t)N_PTS * 256;
    } else {
        T0 = Tin + (size_t)g * N_PTS * 256;
    }

    const int tid = threadIdx.x;
    const int tr  = tid & 15;
    const int tc  = tid >> 4;

    float acc[8][8];
#pragma unroll
    for (int p = 0; p < 8; p++)
#pragma unroll
        for (int q = 0; q < 8; q++) acc[p][q] = 0.f;

    for (int kb = 0; kb < 256; kb += KCT) {
        // stage A (possibly pair-product): 128 rows x 32 cols
#pragma unroll
        for (int i = 0; i < 4; i++) {
            const int idx = tid + i * 256;      // float4 index, 0..1023
            const int row = idx >> 3;
            const int c4  = idx & 7;
            const float4 v0 = *(const float4*)(T0 + (size_t)(n0 + row) * 256 + kb + c4 * 4);
            float4 v = v0;
            if (PAIRED) {
                const float4 v1 = *(const float4*)(T1p + (size_t)(n0 + row) * 256 + kb + c4 * 4);
                v.x *= v1.x; v.y *= v1.y; v.z *= v1.z; v.w *= v1.w;
            }
            sA[c4 * 4 + 0][row] = v.x;
            sA[c4 * 4 + 1][row] = v.y;
            sA[c4 * 4 + 2][row] = v.z;
            sA[c4 * 4 + 3][row] = v.w;
        }
        // stage B: 32 rows (m) x 128 cols (k)
#pragma unroll
        for (int i = 0; i < 4; i++) {
            const int idx = tid + i * 256;
            const int rr  = idx >> 5;
            const int c4  = idx & 31;
            const float4 v = *(const float4*)(Ag + (size_t)(kb + rr) * 256 + k0 + c4 * 4);
            *(float4*)&sB[rr][c4 * 4] = v;
        }
        __syncthreads();
#pragma unroll 8
        for (int kk = 0; kk < KCT; kk++) {
            float a[8], b[8];
            *(float4*)&a[0] = *(const float4*)&sA[kk][tr * 4];
            *(float4*)&a[4] = *(const float4*)&sA[kk][64 + tr * 4];
            *(float4*)&b[0] = *(const float4*)&sB[kk][tc * 4];
            *(float4*)&b[4] = *(const float4*)&sB[kk][64 + tc * 4];
#pragma unroll
            for (int p = 0; p < 8; p++)
#pragma unroll
                for (int q = 0; q < 8; q++) acc[p][q] = fmaf(a[p], b[q], acc[p][q]);
        }
        __syncthreads();
    }

    float* Og = Tout + (size_t)g * N_PTS * 256;
#pragma unroll
    for (int p = 0; p < 8; p++) {
        const int rr = (p < 4) ? (tr * 4 + p) : (64 + tr * 4 + (p - 4));
        float* orow = Og + (size_t)(n0 + rr) * 256 + k0;
        float4 v0 = make_float4(acc[p][0], acc[p][1], acc[p][2], acc[p][3]);
        float4 v1 = make_float4(acc[p][4], acc[p][5], acc[p][6], acc[p][7]);
        *(float4*)(orow + tc * 4)      = v0;
        *(float4*)(orow + 64 + tc * 4) = v1;
    }
}

// ---------------- level 5: pair-product + normalized dot -----------------
__global__ void k_l5(const float* __restrict__ Tin, const float* __restrict__ a5,
                     float* __restrict__ out) {
    const int n = blockIdx.x;
    const int m = threadIdx.x;
    __shared__ float sv[256], sw[256];
    float w = sp10f(a5[m]);
    float v = Tin[(size_t)n * 256 + m] * Tin[(size_t)(N_PTS + n) * 256 + m] * w;
    sv[m] = v;
    sw[m] = w;
    __syncthreads();
    for (int s = 128; s > 0; s >>= 1) {
        if (m < s) { sv[m] += sv[m + s]; sw[m] += sw[m + s]; }
        __syncthreads();
    }
    if (m == 0) out[n] = sv[0] / sw[0];
}

extern "C" void kernel_launch(void* const* d_in, const int* in_sizes, int n_in,
                              void* d_out, int out_size, void* d_ws, size_t ws_size,
                              hipStream_t stream) {
    const float* X  = (const float*)d_in[0];
    const float* wf = (const float*)d_in[1];
    const float* wm = (const float*)d_in[2];
    const float* wl = (const float*)d_in[3];
    const float* b1 = (const float*)d_in[4];
    const float* bm = (const float*)d_in[5];
    const float* bl = (const float*)d_in[6];
    const float* af = (const float*)d_in[7];
    const float* am = (const float*)d_in[8];
    const float* a0 = (const float*)d_in[9];
    const float* a1 = (const float*)d_in[10];
    const float* a2 = (const float*)d_in[11];
    const float* a3 = (const float*)d_in[12];
    const float* a4 = (const float*)d_in[13];
    const float* a5 = (const float*)d_in[14];
    float* out = (float*)d_out;

    float* ws   = (float*)d_ws;
    float* W1t  = ws;                    // 49152
    float* Wmt  = W1t + 49152;           // 294912
    float* Wlt  = Wmt + 294912;          // 49152
    float* Ta1  = Wlt + 49152;           // 49152
    float* Tam  = Ta1 + 49152;           // 98304
    float* csum = Tam + 98304;           // 15872
    float* An   = csum + 15872;          // 62*65536
    float* B0   = An + (size_t)62 * 65536;          // 32*1024*256
    float* B1   = B0 + (size_t)32 * N_PTS * M_DIM;  // 32*1024*256

    k_prep_w<<<512, 256, 0, stream>>>(wf, wm, wl, af, am, W1t, Wmt, Wlt, Ta1, Tam);
    k_csum<<<62, 256, 0, stream>>>(a0, a1, a2, a3, a4, csum);
    k_anorm<<<2048, 256, 0, stream>>>(a0, a1, a2, a3, a4, csum, An);
    k_phase1<<<dim3(32, 32), 256, 0, stream>>>(X, W1t, Wmt, Wlt, b1, bm, bl, Ta1, Tam, B0);

    // HT levels 0..4 (ping-pong B0/B1)
    k_gemm<0><<<dim3(8, 2, 32), 256, 0, stream>>>(B0, An, B1);
    k_gemm<1><<<dim3(8, 2, 16), 256, 0, stream>>>(B1, An + (size_t)32 * 65536, B0);
    k_gemm<1><<<dim3(8, 2, 8),  256, 0, stream>>>(B0, An + (size_t)48 * 65536, B1);
    k_gemm<1><<<dim3(8, 2, 4),  256, 0, stream>>>(B1, An + (size_t)56 * 65536, B0);
    k_gemm<1><<<dim3(8, 2, 2),  256, 0, stream>>>(B0, An + (size_t)60 * 65536, B1);
    // level 5
    k_l5<<<N_PTS, 256, 0, stream>>>(B1, a5, out);
}

// Round 2
// 364.607 us; speedup vs baseline: 1.3673x; 1.3673x over previous
//
#include <hip/hip_runtime.h>
#include <cstdint>
#include <cstddef>

// Problem constants
#define D_DIM 64
#define M_DIM 256
#define N_PTS 1024

static __device__ __forceinline__ float sp10f(float x) {
    // softplus(10x)/10, numerically stable, matches jax.nn.softplus
    float t = 10.f * x;
    return 0.1f * (fmaxf(t, 0.f) + log1pf(__expf(-fabsf(t))));
}

static __device__ __forceinline__ float ftanh(float x) {
    float ax = fminf(fabsf(x), 15.f);
    float e  = __expf(2.f * ax);
    float t  = 1.f - 2.f * __builtin_amdgcn_rcpf(e + 1.f);
    return copysignf(t, x);
}

// map global level-group index g (0..61) -> (raw pointer, local g)
static __device__ __forceinline__ const float* map_g(int g, const float* a0, const float* a1,
                                                     const float* a2, const float* a3,
                                                     const float* a4, int& lg) {
    if (g < 32) { lg = g;      return a0; }
    if (g < 48) { lg = g - 32; return a1; }
    if (g < 56) { lg = g - 48; return a2; }
    if (g < 60) { lg = g - 56; return a3; }
    lg = g - 60; return a4;
}

// ---------------- prep: transform weights (n-independent) ----------------
// Also materializes An = sp10(aHT*) UNNORMALIZED (16 MB); normalization is
// folded into the GEMM epilogue as a divide by csum.
__global__ void k_prep_w(const float* __restrict__ wf, const float* __restrict__ wm,
                         const float* __restrict__ wl, const float* __restrict__ af,
                         const float* __restrict__ am,
                         const float* __restrict__ a0, const float* __restrict__ a1,
                         const float* __restrict__ a2, const float* __restrict__ a3,
                         const float* __restrict__ a4,
                         float* __restrict__ W1t, float* __restrict__ Wmt,
                         float* __restrict__ Wlt, float* __restrict__ Ta1,
                         float* __restrict__ Tam, float* __restrict__ An) {
    const int S0 = 49152, S1 = 294912, S2 = 49152, S3 = 49152, S4 = 98304;
    const int SW = S0 + S1 + S2 + S3 + S4;
    const int total = SW + 62 * 65536;
    for (int i = blockIdx.x * blockDim.x + threadIdx.x; i < total;
         i += gridDim.x * blockDim.x) {
        int j = i;
        if (j < S0) { W1t[j] = sp10f(wf[j]); continue; }
        j -= S0;
        if (j < S1) { Wmt[j] = sp10f(wm[j]); continue; }
        j -= S1;
        if (j < S2) { Wlt[j] = sp10f(wl[j]); continue; }
        j -= S2;
        if (j < S3) { Ta1[j] = tanhf(af[j]); continue; }
        j -= S3;
        if (j < S4) { Tam[j] = tanhf(am[j]); continue; }
        j -= S4;
        // An range: j in [0, 62*65536)
        int g = j >> 16;
        int r = j & 65535;
        int lg;
        const float* A = map_g(g, a0, a1, a2, a3, a4, lg);
        An[j] = sp10f(A[(size_t)lg * 65536 + r]);
    }
}

// partial column sums of An over m. grid (62, 8), block 256 (= k).
__global__ void k_csum_part(const float* __restrict__ An, float* __restrict__ part) {
    const int g = blockIdx.x;
    const int c = blockIdx.y;
    const int k = threadIdx.x;
    const float* base = An + (size_t)g * 65536 + (size_t)c * 32 * 256 + k;
    float s = 0.f;
#pragma unroll
    for (int m = 0; m < 32; m++) s += base[(size_t)m * 256];
    part[((size_t)g * 8 + c) * 256 + k] = s;
}

// reduce the 8 partials. grid 62, block 256.
__global__ void k_csum_red(const float* __restrict__ part, float* __restrict__ csum) {
    const int g = blockIdx.x;
    const int k = threadIdx.x;
    float s = 0.f;
#pragma unroll
    for (int c = 0; c < 8; c++) s += part[((size_t)g * 8 + c) * 256 + k];
    csum[(size_t)g * 256 + k] = s;
}

// ---------------- phase 1: per-(n,d,m) MLP chains, fused d-pair product ---
// grid: (j=0..31, nc=0..31), block 256 threads = m. Output P0[j][n][m].
__global__ __launch_bounds__(256, 3) void k_phase1(
    const float* __restrict__ X, const float* __restrict__ W1t,
    const float* __restrict__ Wmt, const float* __restrict__ Wlt,
    const float* __restrict__ b1, const float* __restrict__ bm,
    const float* __restrict__ bl, const float* __restrict__ Ta1,
    const float* __restrict__ Tam, float* __restrict__ P0) {
    const int m  = threadIdx.x;
    const int j  = blockIdx.x;  // d-pair
    const int nc = blockIdx.y;  // n-chunk (32 n each)
    const int d0 = 2 * j;

    float W1[2][3], Wm[2][2][9], Wl[2][3], B1[2][3], Bm[2][2][3], Bl[2], T1[2][3], Tm[2][2][3];
#pragma unroll
    for (int e = 0; e < 2; e++) {
        const int d  = d0 + e;
        const int dm = d * M_DIM + m;
#pragma unroll
        for (int r = 0; r < 3; r++) {
            W1[e][r] = W1t[dm * 3 + r];
            B1[e][r] = b1[dm * 3 + r];
            T1[e][r] = Ta1[dm * 3 + r];
            Wl[e][r] = Wlt[dm * 3 + r];
        }
        Bl[e] = bl[dm];
#pragma unroll
        for (int l = 0; l < 2; l++) {
            const size_t b9 = ((size_t)(l * D_DIM + d) * M_DIM + m) * 9;
            const size_t b3 = ((size_t)(l * D_DIM + d) * M_DIM + m) * 3;
#pragma unroll
            for (int q = 0; q < 9; q++) Wm[e][l][q] = Wmt[b9 + q];
#pragma unroll
            for (int r = 0; r < 3; r++) {
                Bm[e][l][r] = bm[b3 + r];
                Tm[e][l][r] = Tam[b3 + r];
            }
        }
    }

    float* outp = P0 + ((size_t)j * N_PTS + nc * 32) * M_DIM + m;
    for (int ni = 0; ni < 32; ni++) {
        const int n = nc * 32 + ni;
        float prod[2];
#pragma unroll
        for (int e = 0; e < 2; e++) {
            const float x = X[n * D_DIM + d0 + e];
            float phi[3], pd[3];
#pragma unroll
            for (int r = 0; r < 3; r++) {
                float z  = fmaf(x, W1[e][r], B1[e][r]);
                float tz = ftanh(z);
                float ta = T1[e][r];
                pd[r]  = W1[e][r] * (1.f + ta * (1.f - tz * tz));
                phi[r] = z + tz * ta;
            }
#pragma unroll
            for (int l = 0; l < 2; l++) {
                float nphi[3], npd[3];
#pragma unroll
                for (int q = 0; q < 3; q++) {
                    float z = Bm[e][l][q];
                    float dp = 0.f;
#pragma unroll
                    for (int r = 0; r < 3; r++) {
                        z  = fmaf(phi[r], Wm[e][l][r * 3 + q], z);
                        dp = fmaf(pd[r],  Wm[e][l][r * 3 + q], dp);
                    }
                    float tz = ftanh(z);
                    float ta = Tm[e][l][q];
                    nphi[q] = z + tz * ta;
                    npd[q]  = dp * (1.f + ta * (1.f - tz * tz));
                }
#pragma unroll
                for (int q = 0; q < 3; q++) { phi[q] = nphi[q]; pd[q] = npd[q]; }
            }
            float z = Bl[e], dp = 0.f;
#pragma unroll
            for (int r = 0; r < 3; r++) {
                z  = fmaf(phi[r], Wl[e][r], z);
                dp = fmaf(pd[r],  Wl[e][r], dp);
            }
            float s = __builtin_amdgcn_rcpf(1.f + __expf(-z));
            prod[e] = dp * s * (1.f - s);
        }
        outp[(size_t)ni * M_DIM] = prod[0] * prod[1];
    }
}

// ---------------- phase 2: batched fp32 GEMM -----------------------------
// out[g][n][k] = (sum_m in(g-or-pair)[n][m] * An[g][m][k]) / csum[g][k]
// tile 128x128, KC=32, 256 threads, 8x8 micro-tile (split 4+4).
#define BMT 128
#define BNT 128
#define KCT 32

template <int PAIRED>
__global__ __launch_bounds__(256, 2) void k_gemm(const float* __restrict__ Tin,
                                                 const float* __restrict__ An,
                                                 const float* __restrict__ csum,
                                                 float* __restrict__ Tout) {
    __shared__ float sA[KCT][BMT + 4];
    __shared__ float sB[KCT][BNT + 4];

    const int g  = blockIdx.z;
    const int n0 = blockIdx.x * BMT;
    const int k0 = blockIdx.y * BNT;
    const float* Ag = An + (size_t)g * 65536;
    const float* T0;
    const float* T1p = nullptr;
    if (PAIRED) {
        T0  = Tin + (size_t)(2 * g) * N_PTS * 256;
        T1p = T0 + (size_t)N_PTS * 256;
    } else {
        T0 = Tin + (size_t)g * N_PTS * 256;
    }

    const int tid = threadIdx.x;
    const int tr  = tid & 15;
    const int tc  = tid >> 4;

    float acc[8][8];
#pragma unroll
    for (int p = 0; p < 8; p++)
#pragma unroll
        for (int q = 0; q < 8; q++) acc[p][q] = 0.f;

    for (int kb = 0; kb < 256; kb += KCT) {
        // stage A (possibly pair-product): 128 rows x 32 cols
#pragma unroll
        for (int i = 0; i < 4; i++) {
            const int idx = tid + i * 256;      // float4 index, 0..1023
            const int row = idx >> 3;
            const int c4  = idx & 7;
            const float4 v0 = *(const float4*)(T0 + (size_t)(n0 + row) * 256 + kb + c4 * 4);
            float4 v = v0;
            if (PAIRED) {
                const float4 v1 = *(const float4*)(T1p + (size_t)(n0 + row) * 256 + kb + c4 * 4);
                v.x *= v1.x; v.y *= v1.y; v.z *= v1.z; v.w *= v1.w;
            }
            sA[c4 * 4 + 0][row] = v.x;
            sA[c4 * 4 + 1][row] = v.y;
            sA[c4 * 4 + 2][row] = v.z;
            sA[c4 * 4 + 3][row] = v.w;
        }
        // stage B: 32 rows (m) x 128 cols (k)
#pragma unroll
        for (int i = 0; i < 4; i++) {
            const int idx = tid + i * 256;
            const int rr  = idx >> 5;
            const int c4  = idx & 31;
            const float4 v = *(const float4*)(Ag + (size_t)(kb + rr) * 256 + k0 + c4 * 4);
            *(float4*)&sB[rr][c4 * 4] = v;
        }
        __syncthreads();
#pragma unroll 8
        for (int kk = 0; kk < KCT; kk++) {
            float a[8], b[8];
            *(float4*)&a[0] = *(const float4*)&sA[kk][tr * 4];
            *(float4*)&a[4] = *(const float4*)&sA[kk][64 + tr * 4];
            *(float4*)&b[0] = *(const float4*)&sB[kk][tc * 4];
            *(float4*)&b[4] = *(const float4*)&sB[kk][64 + tc * 4];
#pragma unroll
            for (int p = 0; p < 8; p++)
#pragma unroll
                for (int q = 0; q < 8; q++) acc[p][q] = fmaf(a[p], b[q], acc[p][q]);
        }
        __syncthreads();
    }

    // normalization: divide by column sums
    const float* cs = csum + (size_t)g * 256 + k0;
    float c0[4], c1[4];
    *(float4*)&c0[0] = *(const float4*)&cs[tc * 4];
    *(float4*)&c1[0] = *(const float4*)&cs[64 + tc * 4];

    float* Og = Tout + (size_t)g * N_PTS * 256;
#pragma unroll
    for (int p = 0; p < 8; p++) {
        const int rr = (p < 4) ? (tr * 4 + p) : (64 + tr * 4 + (p - 4));
        float* orow = Og + (size_t)(n0 + rr) * 256 + k0;
        float4 v0 = make_float4(acc[p][0] / c0[0], acc[p][1] / c0[1],
                                acc[p][2] / c0[2], acc[p][3] / c0[3]);
        float4 v1 = make_float4(acc[p][4] / c1[0], acc[p][5] / c1[1],
                                acc[p][6] / c1[2], acc[p][7] / c1[3]);
        *(float4*)(orow + tc * 4)      = v0;
        *(float4*)(orow + 64 + tc * 4) = v1;
    }
}

// ---------------- level 5: pair-product + normalized dot -----------------
__global__ void k_l5(const float* __restrict__ Tin, const float* __restrict__ a5,
                     float* __restrict__ out) {
    const int n = blockIdx.x;
    const int m = threadIdx.x;
    __shared__ float sv[256], sw[256];
    float w = sp10f(a5[m]);
    float v = Tin[(size_t)n * 256 + m] * Tin[(size_t)(N_PTS + n) * 256 + m] * w;
    sv[m] = v;
    sw[m] = w;
    __syncthreads();
    for (int s = 128; s > 0; s >>= 1) {
        if (m < s) { sv[m] += sv[m + s]; sw[m] += sw[m + s]; }
        __syncthreads();
    }
    if (m == 0) out[n] = sv[0] / sw[0];
}

extern "C" void kernel_launch(void* const* d_in, const int* in_sizes, int n_in,
                              void* d_out, int out_size, void* d_ws, size_t ws_size,
                              hipStream_t stream) {
    const float* X  = (const float*)d_in[0];
    const float* wf = (const float*)d_in[1];
    const float* wm = (const float*)d_in[2];
    const float* wl = (const float*)d_in[3];
    const float* b1 = (const float*)d_in[4];
    const float* bm = (const float*)d_in[5];
    const float* bl = (const float*)d_in[6];
    const float* af = (const float*)d_in[7];
    const float* am = (const float*)d_in[8];
    const float* a0 = (const float*)d_in[9];
    const float* a1 = (const float*)d_in[10];
    const float* a2 = (const float*)d_in[11];
    const float* a3 = (const float*)d_in[12];
    const float* a4 = (const float*)d_in[13];
    const float* a5 = (const float*)d_in[14];
    float* out = (float*)d_out;

    float* ws   = (float*)d_ws;
    float* W1t  = ws;                    // 49152
    float* Wmt  = W1t + 49152;           // 294912
    float* Wlt  = Wmt + 294912;          // 49152
    float* Ta1  = Wlt + 49152;           // 49152
    float* Tam  = Ta1 + 49152;           // 98304
    float* part = Tam + 98304;           // 62*8*256 = 126976
    float* csum = part + 126976;         // 15872
    float* An   = csum + 15872;          // 62*65536
    float* B0   = An + (size_t)62 * 65536;          // 32*1024*256
    float* B1   = B0 + (size_t)32 * N_PTS * M_DIM;  // 32*1024*256

    k_prep_w<<<2048, 256, 0, stream>>>(wf, wm, wl, af, am, a0, a1, a2, a3, a4,
                                       W1t, Wmt, Wlt, Ta1, Tam, An);
    k_csum_part<<<dim3(62, 8), 256, 0, stream>>>(An, part);
    k_csum_red<<<62, 256, 0, stream>>>(part, csum);
    k_phase1<<<dim3(32, 32), 256, 0, stream>>>(X, W1t, Wmt, Wlt, b1, bm, bl, Ta1, Tam, B0);

    // HT levels 0..4 (ping-pong B0/B1), normalization fused into epilogue
    k_gemm<0><<<dim3(8, 2, 32), 256, 0, stream>>>(B0, An, csum, B1);
    k_gemm<1><<<dim3(8, 2, 16), 256, 0, stream>>>(B1, An + (size_t)32 * 65536, csum + 32 * 256, B0);
    k_gemm<1><<<dim3(8, 2, 8),  256, 0, stream>>>(B0, An + (size_t)48 * 65536, csum + 48 * 256, B1);
    k_gemm<1><<<dim3(8, 2, 4),  256, 0, stream>>>(B1, An + (size_t)56 * 65536, csum + 56 * 256, B0);
    k_gemm<1><<<dim3(8, 2, 2),  256, 0, stream>>>(B0, An + (size_t)60 * 65536, csum + 60 * 256, B1);
    // level 5
    k_l5<<<N_PTS, 256, 0, stream>>>(B1, a5, out);
}

// Round 3
// 215.295 us; speedup vs baseline: 2.3155x; 1.6935x over previous
//
#include <hip/hip_runtime.h>
#include <cstdint>
#include <cstddef>

// Problem constants
#define D_DIM 64
#define M_DIM 256
#define N_PTS 1024

typedef __attribute__((ext_vector_type(4))) float f32x4;
typedef __attribute__((ext_vector_type(8))) short s16x8;

static __device__ __forceinline__ float sp10f(float x) {
    // softplus(10x)/10, numerically stable, matches jax.nn.softplus
    float t = 10.f * x;
    return 0.1f * (fmaxf(t, 0.f) + log1pf(__expf(-fabsf(t))));
}

// branch-free tanh: 1 - 2/(exp(2x)+1); exact at +-inf (1 / -1), no NaN for finite x
static __device__ __forceinline__ float ftanh(float x) {
    float e = __expf(2.f * x);
    return 1.f - 2.f * __builtin_amdgcn_rcpf(e + 1.f);
}

static __device__ __forceinline__ unsigned short f2bf(float x) {
    unsigned u = __float_as_uint(x);
    u = u + 0x7FFFu + ((u >> 16) & 1u);   // round-to-nearest-even
    return (unsigned short)(u >> 16);
}
static __device__ __forceinline__ float bf2f(unsigned short h) {
    return __uint_as_float(((unsigned)h) << 16);
}

// map global level-group index g (0..61) -> (raw pointer, local g)
static __device__ __forceinline__ const float* map_g(int g, const float* a0, const float* a1,
                                                     const float* a2, const float* a3,
                                                     const float* a4, int& lg) {
    if (g < 32) { lg = g;      return a0; }
    if (g < 48) { lg = g - 32; return a1; }
    if (g < 56) { lg = g - 48; return a2; }
    if (g < 60) { lg = g - 56; return a3; }
    lg = g - 60; return a4;
}

// ---------------- prep: transform MLP weights (n-independent) -------------
__global__ void k_prep_w(const float* __restrict__ wf, const float* __restrict__ wm,
                         const float* __restrict__ wl, const float* __restrict__ af,
                         const float* __restrict__ am,
                         float* __restrict__ W1t, float* __restrict__ Wmt,
                         float* __restrict__ Wlt, float* __restrict__ Ta1,
                         float* __restrict__ Tam) {
    const int S0 = 49152, S1 = 294912, S2 = 49152, S3 = 49152, S4 = 98304;
    const int total = S0 + S1 + S2 + S3 + S4;
    for (int i = blockIdx.x * blockDim.x + threadIdx.x; i < total;
         i += gridDim.x * blockDim.x) {
        int j = i;
        if (j < S0) { W1t[j] = sp10f(wf[j]); continue; }
        j -= S0;
        if (j < S1) { Wmt[j] = sp10f(wm[j]); continue; }
        j -= S1;
        if (j < S2) { Wlt[j] = sp10f(wl[j]); continue; }
        j -= S2;
        if (j < S3) { Ta1[j] = tanhf(af[j]); continue; }
        j -= S3;
        Tam[j] = tanhf(am[j]);
    }
}

// ---------------- transpose + bf16-split the HT mixing matrices ----------
// An_t[g][k][m] (hi/lo bf16) = split(sp10(aHT[g][m][k])). Output-coalesced;
// strided input reads are L2-served (16 MB working set).
__global__ void k_transp(const float* __restrict__ a0, const float* __restrict__ a1,
                         const float* __restrict__ a2, const float* __restrict__ a3,
                         const float* __restrict__ a4,
                         unsigned short* __restrict__ Anth,
                         unsigned short* __restrict__ Antl) {
    const int total = 62 * 65536;
    for (int i = blockIdx.x * blockDim.x + threadIdx.x; i < total;
         i += gridDim.x * blockDim.x) {
        int g = i >> 16;
        int r = i & 65535;
        int k = r >> 8;
        int m = r & 255;
        int lg;
        const float* A = map_g(g, a0, a1, a2, a3, a4, lg);
        float v = sp10f(A[(size_t)lg * 65536 + m * 256 + k]);
        unsigned short h = f2bf(v);
        Anth[i] = h;
        Antl[i] = f2bf(v - bf2f(h));
    }
}

// column sums (over m) from transposed hi/lo rows. grid (62,64), 4 waves/blk,
// one k-row per wave, contiguous 8B loads + wave shuffle reduce.
__global__ void k_csum_t(const unsigned short* __restrict__ Anth,
                         const unsigned short* __restrict__ Antl,
                         float* __restrict__ csum) {
    const int g    = blockIdx.x;
    const int w    = threadIdx.x >> 6;
    const int lane = threadIdx.x & 63;
    const int k    = blockIdx.y * 4 + w;
    const size_t base = (size_t)g * 65536 + k * 256 + lane * 4;
    uint2 vh = *(const uint2*)(Anth + base);
    uint2 vl = *(const uint2*)(Antl + base);
    float s = 0.f;
    s += bf2f((unsigned short)(vh.x & 0xFFFFu)) + bf2f((unsigned short)(vh.x >> 16));
    s += bf2f((unsigned short)(vh.y & 0xFFFFu)) + bf2f((unsigned short)(vh.y >> 16));
    s += bf2f((unsigned short)(vl.x & 0xFFFFu)) + bf2f((unsigned short)(vl.x >> 16));
    s += bf2f((unsigned short)(vl.y & 0xFFFFu)) + bf2f((unsigned short)(vl.y >> 16));
    for (int off = 32; off > 0; off >>= 1) s += __shfl_down(s, off);
    if (lane == 0) csum[g * 256 + k] = s;
}

// ---------------- phase 1: per-(n,d,m) MLP chains, fused d-pair product ---
// grid: (j=0..31, nc=0..31), block 256 threads = m. Output P0[j][n][m].
__global__ __launch_bounds__(256, 3) void k_phase1(
    const float* __restrict__ X, const float* __restrict__ W1t,
    const float* __restrict__ Wmt, const float* __restrict__ Wlt,
    const float* __restrict__ b1, const float* __restrict__ bm,
    const float* __restrict__ bl, const float* __restrict__ Ta1,
    const float* __restrict__ Tam, float* __restrict__ P0) {
    const int m  = threadIdx.x;
    const int j  = blockIdx.x;  // d-pair
    const int nc = blockIdx.y;  // n-chunk (32 n each)
    const int d0 = 2 * j;

    __shared__ float sX[32][2];
    if (threadIdx.x < 64)
        sX[threadIdx.x >> 1][threadIdx.x & 1] =
            X[(nc * 32 + (threadIdx.x >> 1)) * D_DIM + d0 + (threadIdx.x & 1)];

    float W1[2][3], Wm[2][2][9], Wl[2][3], B1[2][3], Bm[2][2][3], Bl[2], T1[2][3], Tm[2][2][3];
#pragma unroll
    for (int e = 0; e < 2; e++) {
        const int d  = d0 + e;
        const int dm = d * M_DIM + m;
#pragma unroll
        for (int r = 0; r < 3; r++) {
            W1[e][r] = W1t[dm * 3 + r];
            B1[e][r] = b1[dm * 3 + r];
            T1[e][r] = Ta1[dm * 3 + r];
            Wl[e][r] = Wlt[dm * 3 + r];
        }
        Bl[e] = bl[dm];
#pragma unroll
        for (int l = 0; l < 2; l++) {
            const size_t b9 = ((size_t)(l * D_DIM + d) * M_DIM + m) * 9;
            const size_t b3 = ((size_t)(l * D_DIM + d) * M_DIM + m) * 3;
#pragma unroll
            for (int q = 0; q < 9; q++) Wm[e][l][q] = Wmt[b9 + q];
#pragma unroll
            for (int r = 0; r < 3; r++) {
                Bm[e][l][r] = bm[b3 + r];
                Tm[e][l][r] = Tam[b3 + r];
            }
        }
    }
    __syncthreads();

    float* outp = P0 + ((size_t)j * N_PTS + nc * 32) * M_DIM + m;
    for (int ni = 0; ni < 32; ni += 2) {
        float prod[2][2];
#pragma unroll
        for (int u = 0; u < 2; u++) {
#pragma unroll
            for (int e = 0; e < 2; e++) {
                const float x = sX[ni + u][e];
                float phi[3], pd[3];
#pragma unroll
                for (int r = 0; r < 3; r++) {
                    float z  = fmaf(x, W1[e][r], B1[e][r]);
                    float tz = ftanh(z);
                    float ta = T1[e][r];
                    pd[r]  = W1[e][r] * fmaf(ta, fmaf(-tz, tz, 1.f), 1.f);
                    phi[r] = z + tz * ta;
                }
#pragma unroll
                for (int l = 0; l < 2; l++) {
                    float nphi[3], npd[3];
#pragma unroll
                    for (int q = 0; q < 3; q++) {
                        float z = Bm[e][l][q];
                        float dp = 0.f;
#pragma unroll
                        for (int r = 0; r < 3; r++) {
                            z  = fmaf(phi[r], Wm[e][l][r * 3 + q], z);
                            dp = fmaf(pd[r],  Wm[e][l][r * 3 + q], dp);
                        }
                        float tz = ftanh(z);
                        float ta = Tm[e][l][q];
                        nphi[q] = z + tz * ta;
                        npd[q]  = dp * fmaf(ta, fmaf(-tz, tz, 1.f), 1.f);
                    }
#pragma unroll
                    for (int q = 0; q < 3; q++) { phi[q] = nphi[q]; pd[q] = npd[q]; }
                }
                float z = Bl[e], dp = 0.f;
#pragma unroll
                for (int r = 0; r < 3; r++) {
                    z  = fmaf(phi[r], Wl[e][r], z);
                    dp = fmaf(pd[r],  Wl[e][r], dp);
                }
                float s = __builtin_amdgcn_rcpf(1.f + __expf(-z));
                prod[u][e] = dp * s * (1.f - s);
            }
        }
        outp[(size_t)ni * M_DIM]       = prod[0][0] * prod[0][1];
        outp[(size_t)(ni + 1) * M_DIM] = prod[1][0] * prod[1][1];
    }
}

// ---------------- phase 2: batched bf16x3 MFMA GEMM ----------------------
// out[g][n][k] = (sum_m Tpair[n][m] * An[g][m][k]) / csum[g][k]
// C = Th*Ah + Th*Al + Tl*Ah  (bf16 hi/lo split, fp32 accumulate)
// block: 256 thr = 4 waves (2x2), tile 128n x 128k, K-step 32 m.
#define LDST 40  // LDS row stride in bf16 elems (32 + 8 pad = 80 B)

template <int PAIRED>
__global__ __launch_bounds__(256, 2) void k_gemm(const float* __restrict__ Tin,
                                                 const unsigned short* __restrict__ Bh,
                                                 const unsigned short* __restrict__ Bl,
                                                 const float* __restrict__ csum,
                                                 float* __restrict__ Tout) {
    __shared__ unsigned short sAh[128 * LDST];
    __shared__ unsigned short sAl[128 * LDST];
    __shared__ unsigned short sBh[128 * LDST];
    __shared__ unsigned short sBl[128 * LDST];

    const int g  = blockIdx.z;
    const int n0 = blockIdx.x * 128;
    const int k0 = blockIdx.y * 128;
    const float* T0 = PAIRED ? Tin + (size_t)(2 * g) * N_PTS * 256
                             : Tin + (size_t)g * N_PTS * 256;
    const float* T1p = PAIRED ? T0 + (size_t)N_PTS * 256 : nullptr;
    const unsigned short* Bhg = Bh + (size_t)g * 65536;
    const unsigned short* Blg = Bl + (size_t)g * 65536;

    const int tid  = threadIdx.x;
    const int lane = tid & 63;
    const int w    = tid >> 6;
    const int wr   = w >> 1;   // n-half of tile
    const int wc   = w & 1;    // k-half of tile
    const int lr   = lane & 15;
    const int lk   = lane >> 4;

    f32x4 acc[4][4];
#pragma unroll
    for (int a = 0; a < 4; a++)
#pragma unroll
        for (int b = 0; b < 4; b++) acc[a][b] = (f32x4){0.f, 0.f, 0.f, 0.f};

    for (int kb = 0; kb < 256; kb += 32) {
        // stage A: 128 n x 32 m fp32 (pair-multiplied) -> hi/lo bf16 LDS
#pragma unroll
        for (int i = 0; i < 4; i++) {
            const int idx = i * 256 + tid;
            const int row = idx >> 3;
            const int m4  = idx & 7;
            float4 v = *(const float4*)(T0 + (size_t)(n0 + row) * 256 + kb + m4 * 4);
            if (PAIRED) {
                float4 u = *(const float4*)(T1p + (size_t)(n0 + row) * 256 + kb + m4 * 4);
                v.x *= u.x; v.y *= u.y; v.z *= u.z; v.w *= u.w;
            }
            unsigned short h0 = f2bf(v.x), h1 = f2bf(v.y), h2 = f2bf(v.z), h3 = f2bf(v.w);
            uint2 hp, lp;
            hp.x = (unsigned)h0 | ((unsigned)h1 << 16);
            hp.y = (unsigned)h2 | ((unsigned)h3 << 16);
            lp.x = (unsigned)f2bf(v.x - bf2f(h0)) | ((unsigned)f2bf(v.y - bf2f(h1)) << 16);
            lp.y = (unsigned)f2bf(v.z - bf2f(h2)) | ((unsigned)f2bf(v.w - bf2f(h3)) << 16);
            *(uint2*)&sAh[row * LDST + m4 * 4] = hp;
            *(uint2*)&sAl[row * LDST + m4 * 4] = lp;
        }
        // stage B: 128 k x 32 m bf16 hi/lo (already split/transposed)
#pragma unroll
        for (int i = 0; i < 2; i++) {
            const int idx  = i * 256 + tid;
            const int krow = idx >> 2;
            const int seg  = idx & 3;
            const size_t src = (size_t)(k0 + krow) * 256 + kb + seg * 8;
            *(uint4*)&sBh[krow * LDST + seg * 8] = *(const uint4*)(Bhg + src);
            *(uint4*)&sBl[krow * LDST + seg * 8] = *(const uint4*)(Blg + src);
        }
        __syncthreads();

        s16x8 ah[4], al[4], bh[4], bl[4];
#pragma unroll
        for (int nt = 0; nt < 4; nt++) {
            const int off = (wr * 64 + nt * 16 + lr) * LDST + lk * 8;
            ah[nt] = *(const s16x8*)&sAh[off];
            al[nt] = *(const s16x8*)&sAl[off];
        }
#pragma unroll
        for (int kt = 0; kt < 4; kt++) {
            const int off = (wc * 64 + kt * 16 + lr) * LDST + lk * 8;
            bh[kt] = *(const s16x8*)&sBh[off];
            bl[kt] = *(const s16x8*)&sBl[off];
        }
#pragma unroll
        for (int nt = 0; nt < 4; nt++)
#pragma unroll
            for (int kt = 0; kt < 4; kt++) {
                acc[nt][kt] = __builtin_amdgcn_mfma_f32_16x16x32_bf16(ah[nt], bh[kt], acc[nt][kt], 0, 0, 0);
                acc[nt][kt] = __builtin_amdgcn_mfma_f32_16x16x32_bf16(ah[nt], bl[kt], acc[nt][kt], 0, 0, 0);
                acc[nt][kt] = __builtin_amdgcn_mfma_f32_16x16x32_bf16(al[nt], bh[kt], acc[nt][kt], 0, 0, 0);
            }
        __syncthreads();
    }

    // epilogue: normalize by column sum, scattered 4B stores (16-lane coalesced)
    float* Og = Tout + (size_t)g * N_PTS * 256;
#pragma unroll
    for (int kt = 0; kt < 4; kt++) {
        const int col = k0 + wc * 64 + kt * 16 + lr;
        const float inv = 1.0f / csum[g * 256 + col];
#pragma unroll
        for (int nt = 0; nt < 4; nt++) {
            const int rbase = n0 + wr * 64 + nt * 16 + lk * 4;
#pragma unroll
            for (int r = 0; r < 4; r++)
                Og[(size_t)(rbase + r) * 256 + col] = acc[nt][kt][r] * inv;
        }
    }
}

// ---------------- level 5: pair-product + normalized dot -----------------
__global__ void k_l5(const float* __restrict__ Tin, const float* __restrict__ a5,
                     float* __restrict__ out) {
    const int n = blockIdx.x;
    const int m = threadIdx.x;
    __shared__ float sv[256], sw[256];
    float w = sp10f(a5[m]);
    float v = Tin[(size_t)n * 256 + m] * Tin[(size_t)(N_PTS + n) * 256 + m] * w;
    sv[m] = v;
    sw[m] = w;
    __syncthreads();
    for (int s = 128; s > 0; s >>= 1) {
        if (m < s) { sv[m] += sv[m + s]; sw[m] += sw[m + s]; }
        __syncthreads();
    }
    if (m == 0) out[n] = sv[0] / sw[0];
}

extern "C" void kernel_launch(void* const* d_in, const int* in_sizes, int n_in,
                              void* d_out, int out_size, void* d_ws, size_t ws_size,
                              hipStream_t stream) {
    const float* X  = (const float*)d_in[0];
    const float* wf = (const float*)d_in[1];
    const float* wm = (const float*)d_in[2];
    const float* wl = (const float*)d_in[3];
    const float* b1 = (const float*)d_in[4];
    const float* bm = (const float*)d_in[5];
    const float* bl = (const float*)d_in[6];
    const float* af = (const float*)d_in[7];
    const float* am = (const float*)d_in[8];
    const float* a0 = (const float*)d_in[9];
    const float* a1 = (const float*)d_in[10];
    const float* a2 = (const float*)d_in[11];
    const float* a3 = (const float*)d_in[12];
    const float* a4 = (const float*)d_in[13];
    const float* a5 = (const float*)d_in[14];
    float* out = (float*)d_out;

    float* ws   = (float*)d_ws;
    float* W1t  = ws;                    // 49152
    float* Wmt  = W1t + 49152;           // 294912
    float* Wlt  = Wmt + 294912;          // 49152
    float* Ta1  = Wlt + 49152;           // 49152
    float* Tam  = Ta1 + 49152;           // 98304
    float* csum = Tam + 98304;           // 15872
    unsigned short* Anth = (unsigned short*)(csum + 15872);  // 62*65536 ushort
    unsigned short* Antl = Anth + (size_t)62 * 65536;        // 62*65536 ushort
    float* B0   = (float*)(Antl + (size_t)62 * 65536);       // 32*1024*256
    float* B1   = B0 + (size_t)32 * N_PTS * M_DIM;           // 32*1024*256

    k_prep_w<<<512, 256, 0, stream>>>(wf, wm, wl, af, am, W1t, Wmt, Wlt, Ta1, Tam);
    k_transp<<<2048, 256, 0, stream>>>(a0, a1, a2, a3, a4, Anth, Antl);
    k_csum_t<<<dim3(62, 64), 256, 0, stream>>>(Anth, Antl, csum);
    k_phase1<<<dim3(32, 32), 256, 0, stream>>>(X, W1t, Wmt, Wlt, b1, bm, bl, Ta1, Tam, B0);

    // HT levels 0..4 (ping-pong B0/B1), normalization fused into epilogue
    k_gemm<0><<<dim3(8, 2, 32), 256, 0, stream>>>(B0, Anth, Antl, csum, B1);
    k_gemm<1><<<dim3(8, 2, 16), 256, 0, stream>>>(B1, Anth + (size_t)32 * 65536,
                                                  Antl + (size_t)32 * 65536, csum + 32 * 256, B0);
    k_gemm<1><<<dim3(8, 2, 8),  256, 0, stream>>>(B0, Anth + (size_t)48 * 65536,
                                                  Antl + (size_t)48 * 65536, csum + 48 * 256, B1);
    k_gemm<1><<<dim3(8, 2, 4),  256, 0, stream>>>(B1, Anth + (size_t)56 * 65536,
                                                  Antl + (size_t)56 * 65536, csum + 56 * 256, B0);
    k_gemm<1><<<dim3(8, 2, 2),  256, 0, stream>>>(B0, Anth + (size_t)60 * 65536,
                                                  Antl + (size_t)60 * 65536, csum + 60 * 256, B1);
    // level 5
    k_l5<<<N_PTS, 256, 0, stream>>>(B1, a5, out);
}

// Round 4
// 212.230 us; speedup vs baseline: 2.3489x; 1.0144x over previous
//
#include <hip/hip_runtime.h>
#include <cstdint>
#include <cstddef>

// Problem constants
#define D_DIM 64
#define M_DIM 256
#define N_PTS 1024

typedef __attribute__((ext_vector_type(4))) float f32x4;
typedef __attribute__((ext_vector_type(8))) short s16x8;

static __device__ __forceinline__ float sp10f(float x) {
    // softplus(10x)/10, numerically stable, matches jax.nn.softplus
    float t = 10.f * x;
    return 0.1f * (fmaxf(t, 0.f) + log1pf(__expf(-fabsf(t))));
}

// branch-free tanh: 1 - 2/(exp(2x)+1); exact at +-inf (1 / -1), no NaN for finite x
static __device__ __forceinline__ float ftanh(float x) {
    float e = __expf(2.f * x);
    return 1.f - 2.f * __builtin_amdgcn_rcpf(e + 1.f);
}

static __device__ __forceinline__ unsigned short f2bf(float x) {
    unsigned u = __float_as_uint(x);
    u = u + 0x7FFFu + ((u >> 16) & 1u);   // round-to-nearest-even
    return (unsigned short)(u >> 16);
}
static __device__ __forceinline__ float bf2f(unsigned short h) {
    return __uint_as_float(((unsigned)h) << 16);
}

// map global level-group index g (0..61) -> (raw pointer, local g)
static __device__ __forceinline__ const float* map_g(int g, const float* a0, const float* a1,
                                                     const float* a2, const float* a3,
                                                     const float* a4, int& lg) {
    if (g < 32) { lg = g;      return a0; }
    if (g < 48) { lg = g - 32; return a1; }
    if (g < 56) { lg = g - 48; return a2; }
    if (g < 60) { lg = g - 56; return a3; }
    lg = g - 60; return a4;
}

// ---------------- prep: MLP weights + HT transpose/bf16-split ------------
__global__ void k_prep(const float* __restrict__ wf, const float* __restrict__ wm,
                       const float* __restrict__ wl, const float* __restrict__ af,
                       const float* __restrict__ am,
                       const float* __restrict__ a0, const float* __restrict__ a1,
                       const float* __restrict__ a2, const float* __restrict__ a3,
                       const float* __restrict__ a4,
                       float* __restrict__ W1t, float* __restrict__ Wmt,
                       float* __restrict__ Wlt, float* __restrict__ Ta1,
                       float* __restrict__ Tam,
                       unsigned short* __restrict__ Anth,
                       unsigned short* __restrict__ Antl) {
    const int S0 = 49152, S1 = 294912, S2 = 49152, S3 = 49152, S4 = 98304;
    const int SW = S0 + S1 + S2 + S3 + S4;
    const int total = SW + 62 * 65536;
    for (int i = blockIdx.x * blockDim.x + threadIdx.x; i < total;
         i += gridDim.x * blockDim.x) {
        int j = i;
        if (j < S0) { W1t[j] = sp10f(wf[j]); continue; }
        j -= S0;
        if (j < S1) { Wmt[j] = sp10f(wm[j]); continue; }
        j -= S1;
        if (j < S2) { Wlt[j] = sp10f(wl[j]); continue; }
        j -= S2;
        if (j < S3) { Ta1[j] = tanhf(af[j]); continue; }
        j -= S3;
        if (j < S4) { Tam[j] = tanhf(am[j]); continue; }
        j -= S4;
        // transposed HT matrices: j indexes [g][k][m]
        int g = j >> 16;
        int r = j & 65535;
        int k = r >> 8;
        int m = r & 255;
        int lg;
        const float* A = map_g(g, a0, a1, a2, a3, a4, lg);
        float v = sp10f(A[(size_t)lg * 65536 + m * 256 + k]);
        unsigned short h = f2bf(v);
        Anth[j] = h;
        Antl[j] = f2bf(v - bf2f(h));
    }
}

// column sums (over m) from transposed hi/lo rows. grid (62,64), 4 waves/blk,
// one k-row per wave, contiguous 8B loads + wave shuffle reduce.
__global__ void k_csum_t(const unsigned short* __restrict__ Anth,
                         const unsigned short* __restrict__ Antl,
                         float* __restrict__ csum) {
    const int g    = blockIdx.x;
    const int w    = threadIdx.x >> 6;
    const int lane = threadIdx.x & 63;
    const int k    = blockIdx.y * 4 + w;
    const size_t base = (size_t)g * 65536 + k * 256 + lane * 4;
    uint2 vh = *(const uint2*)(Anth + base);
    uint2 vl = *(const uint2*)(Antl + base);
    float s = 0.f;
    s += bf2f((unsigned short)(vh.x & 0xFFFFu)) + bf2f((unsigned short)(vh.x >> 16));
    s += bf2f((unsigned short)(vh.y & 0xFFFFu)) + bf2f((unsigned short)(vh.y >> 16));
    s += bf2f((unsigned short)(vl.x & 0xFFFFu)) + bf2f((unsigned short)(vl.x >> 16));
    s += bf2f((unsigned short)(vl.y & 0xFFFFu)) + bf2f((unsigned short)(vl.y >> 16));
    for (int off = 32; off > 0; off >>= 1) s += __shfl_down(s, off);
    if (lane == 0) csum[g * 256 + k] = s;
}

// ---------------- phase 1: one (d,m) chain per thread --------------------
// grid: (j=0..31, nc=0..31, mb=0..1), block 256 = 128 m x 2 e.
// thread (mh,e) runs chain for d=2j+e, m=mb*128+mh over 32 n; pair product
// via __shfl_xor(.,1); even lanes store P0[j][n][m].
__global__ __launch_bounds__(256, 4) void k_phase1(
    const float* __restrict__ X, const float* __restrict__ W1t,
    const float* __restrict__ Wmt, const float* __restrict__ Wlt,
    const float* __restrict__ b1, const float* __restrict__ bm,
    const float* __restrict__ bl, const float* __restrict__ Ta1,
    const float* __restrict__ Tam, float* __restrict__ P0) {
    const int t  = threadIdx.x;
    const int e  = t & 1;
    const int mh = t >> 1;
    const int j  = blockIdx.x;
    const int nc = blockIdx.y;
    const int mb = blockIdx.z;
    const int m  = mb * 128 + mh;
    const int d  = 2 * j + e;
    const int dm = d * M_DIM + m;

    __shared__ float sX[32][2];
    if (t < 64)
        sX[t >> 1][t & 1] = X[(nc * 32 + (t >> 1)) * D_DIM + 2 * j + (t & 1)];

    float W1[3], Wm[2][9], Wl[3], B1[3], Bm[2][3], T1[3], Tm[2][3], Blast;
#pragma unroll
    for (int r = 0; r < 3; r++) {
        W1[r] = W1t[dm * 3 + r];
        B1[r] = b1[dm * 3 + r];
        T1[r] = Ta1[dm * 3 + r];
        Wl[r] = Wlt[dm * 3 + r];
    }
    Blast = bl[dm];
#pragma unroll
    for (int l = 0; l < 2; l++) {
        const size_t b9 = ((size_t)(l * D_DIM + d) * M_DIM + m) * 9;
        const size_t b3 = ((size_t)(l * D_DIM + d) * M_DIM + m) * 3;
#pragma unroll
        for (int q = 0; q < 9; q++) Wm[l][q] = Wmt[b9 + q];
#pragma unroll
        for (int r = 0; r < 3; r++) {
            Bm[l][r] = bm[b3 + r];
            Tm[l][r] = Tam[b3 + r];
        }
    }
    __syncthreads();

    float* outp = P0 + ((size_t)j * N_PTS + nc * 32) * M_DIM + m;
    for (int ni = 0; ni < 32; ni++) {
        const float x = sX[ni][e];
        float phi[3], pd[3];
#pragma unroll
        for (int r = 0; r < 3; r++) {
            float z  = fmaf(x, W1[r], B1[r]);
            float tz = ftanh(z);
            float ta = T1[r];
            pd[r]  = W1[r] * fmaf(ta, fmaf(-tz, tz, 1.f), 1.f);
            phi[r] = z + tz * ta;
        }
#pragma unroll
        for (int l = 0; l < 2; l++) {
            float nphi[3], npd[3];
#pragma unroll
            for (int q = 0; q < 3; q++) {
                float z = Bm[l][q];
                float dp = 0.f;
#pragma unroll
                for (int r = 0; r < 3; r++) {
                    z  = fmaf(phi[r], Wm[l][r * 3 + q], z);
                    dp = fmaf(pd[r],  Wm[l][r * 3 + q], dp);
                }
                float tz = ftanh(z);
                float ta = Tm[l][q];
                nphi[q] = z + tz * ta;
                npd[q]  = dp * fmaf(ta, fmaf(-tz, tz, 1.f), 1.f);
            }
#pragma unroll
            for (int q = 0; q < 3; q++) { phi[q] = nphi[q]; pd[q] = npd[q]; }
        }
        float z = Blast, dp = 0.f;
#pragma unroll
        for (int r = 0; r < 3; r++) {
            z  = fmaf(phi[r], Wl[r], z);
            dp = fmaf(pd[r],  Wl[r], dp);
        }
        float s = __builtin_amdgcn_rcpf(1.f + __expf(-z));
        float prod = dp * s * (1.f - s);
        float other = __shfl_xor(prod, 1);
        if (e == 0) outp[(size_t)ni * M_DIM] = prod * other;
    }
}

// ---------------- phase 2: batched bf16x3 MFMA GEMM ----------------------
// out[g][n][k] = (sum_m Tpair[n][m] * An[g][m][k]) / csum[g][k]
// C = Th*Ah + Th*Al + Tl*Ah  (bf16 hi/lo split, fp32 accumulate)
// block: 256 thr = 4 waves (2x2), tile 128n x 128k, K-step 32 m.
#define LDST 40  // LDS row stride in bf16 elems (32 + 8 pad = 80 B)

template <int PAIRED>
__global__ __launch_bounds__(256, 2) void k_gemm(const float* __restrict__ Tin,
                                                 const unsigned short* __restrict__ Bh,
                                                 const unsigned short* __restrict__ Bl,
                                                 const float* __restrict__ csum,
                                                 float* __restrict__ Tout) {
    __shared__ unsigned short sAh[128 * LDST];
    __shared__ unsigned short sAl[128 * LDST];
    __shared__ unsigned short sBh[128 * LDST];
    __shared__ unsigned short sBl[128 * LDST];

    const int g  = blockIdx.z;
    const int n0 = blockIdx.x * 128;
    const int k0 = blockIdx.y * 128;
    const float* T0 = PAIRED ? Tin + (size_t)(2 * g) * N_PTS * 256
                             : Tin + (size_t)g * N_PTS * 256;
    const float* T1p = PAIRED ? T0 + (size_t)N_PTS * 256 : nullptr;
    const unsigned short* Bhg = Bh + (size_t)g * 65536;
    const unsigned short* Blg = Bl + (size_t)g * 65536;

    const int tid  = threadIdx.x;
    const int lane = tid & 63;
    const int w    = tid >> 6;
    const int wr   = w >> 1;   // n-half of tile
    const int wc   = w & 1;    // k-half of tile
    const int lr   = lane & 15;
    const int lk   = lane >> 4;

    f32x4 acc[4][4];
#pragma unroll
    for (int a = 0; a < 4; a++)
#pragma unroll
        for (int b = 0; b < 4; b++) acc[a][b] = (f32x4){0.f, 0.f, 0.f, 0.f};

    for (int kb = 0; kb < 256; kb += 32) {
        // stage A: 128 n x 32 m fp32 (pair-multiplied) -> hi/lo bf16 LDS
#pragma unroll
        for (int i = 0; i < 4; i++) {
            const int idx = i * 256 + tid;
            const int row = idx >> 3;
            const int m4  = idx & 7;
            float4 v = *(const float4*)(T0 + (size_t)(n0 + row) * 256 + kb + m4 * 4);
            if (PAIRED) {
                float4 u = *(const float4*)(T1p + (size_t)(n0 + row) * 256 + kb + m4 * 4);
                v.x *= u.x; v.y *= u.y; v.z *= u.z; v.w *= u.w;
            }
            unsigned short h0 = f2bf(v.x), h1 = f2bf(v.y), h2 = f2bf(v.z), h3 = f2bf(v.w);
            uint2 hp, lp;
            hp.x = (unsigned)h0 | ((unsigned)h1 << 16);
            hp.y = (unsigned)h2 | ((unsigned)h3 << 16);
            lp.x = (unsigned)f2bf(v.x - bf2f(h0)) | ((unsigned)f2bf(v.y - bf2f(h1)) << 16);
            lp.y = (unsigned)f2bf(v.z - bf2f(h2)) | ((unsigned)f2bf(v.w - bf2f(h3)) << 16);
            *(uint2*)&sAh[row * LDST + m4 * 4] = hp;
            *(uint2*)&sAl[row * LDST + m4 * 4] = lp;
        }
        // stage B: 128 k x 32 m bf16 hi/lo (already split/transposed)
#pragma unroll
        for (int i = 0; i < 2; i++) {
            const int idx  = i * 256 + tid;
            const int krow = idx >> 2;
            const int seg  = idx & 3;
            const size_t src = (size_t)(k0 + krow) * 256 + kb + seg * 8;
            *(uint4*)&sBh[krow * LDST + seg * 8] = *(const uint4*)(Bhg + src);
            *(uint4*)&sBl[krow * LDST + seg * 8] = *(const uint4*)(Blg + src);
        }
        __syncthreads();

        s16x8 ah[4], al[4], bh[4], bl[4];
#pragma unroll
        for (int nt = 0; nt < 4; nt++) {
            const int off = (wr * 64 + nt * 16 + lr) * LDST + lk * 8;
            ah[nt] = *(const s16x8*)&sAh[off];
            al[nt] = *(const s16x8*)&sAl[off];
        }
#pragma unroll
        for (int kt = 0; kt < 4; kt++) {
            const int off = (wc * 64 + kt * 16 + lr) * LDST + lk * 8;
            bh[kt] = *(const s16x8*)&sBh[off];
            bl[kt] = *(const s16x8*)&sBl[off];
        }
#pragma unroll
        for (int nt = 0; nt < 4; nt++)
#pragma unroll
            for (int kt = 0; kt < 4; kt++) {
                acc[nt][kt] = __builtin_amdgcn_mfma_f32_16x16x32_bf16(ah[nt], bh[kt], acc[nt][kt], 0, 0, 0);
                acc[nt][kt] = __builtin_amdgcn_mfma_f32_16x16x32_bf16(ah[nt], bl[kt], acc[nt][kt], 0, 0, 0);
                acc[nt][kt] = __builtin_amdgcn_mfma_f32_16x16x32_bf16(al[nt], bh[kt], acc[nt][kt], 0, 0, 0);
            }
        __syncthreads();
    }

    // epilogue: normalize by column sum, scattered 4B stores (16-lane coalesced)
    float* Og = Tout + (size_t)g * N_PTS * 256;
#pragma unroll
    for (int kt = 0; kt < 4; kt++) {
        const int col = k0 + wc * 64 + kt * 16 + lr;
        const float inv = 1.0f / csum[g * 256 + col];
#pragma unroll
        for (int nt = 0; nt < 4; nt++) {
            const int rbase = n0 + wr * 64 + nt * 16 + lk * 4;
#pragma unroll
            for (int r = 0; r < 4; r++)
                Og[(size_t)(rbase + r) * 256 + col] = acc[nt][kt][r] * inv;
        }
    }
}

// ---------------- level 5: pair-product + normalized dot -----------------
__global__ void k_l5(const float* __restrict__ Tin, const float* __restrict__ a5,
                     float* __restrict__ out) {
    const int n = blockIdx.x;
    const int m = threadIdx.x;
    __shared__ float sv[256], sw[256];
    float w = sp10f(a5[m]);
    float v = Tin[(size_t)n * 256 + m] * Tin[(size_t)(N_PTS + n) * 256 + m] * w;
    sv[m] = v;
    sw[m] = w;
    __syncthreads();
    for (int s = 128; s > 0; s >>= 1) {
        if (m < s) { sv[m] += sv[m + s]; sw[m] += sw[m + s]; }
        __syncthreads();
    }
    if (m == 0) out[n] = sv[0] / sw[0];
}

extern "C" void kernel_launch(void* const* d_in, const int* in_sizes, int n_in,
                              void* d_out, int out_size, void* d_ws, size_t ws_size,
                              hipStream_t stream) {
    const float* X  = (const float*)d_in[0];
    const float* wf = (const float*)d_in[1];
    const float* wm = (const float*)d_in[2];
    const float* wl = (const float*)d_in[3];
    const float* b1 = (const float*)d_in[4];
    const float* bm = (const float*)d_in[5];
    const float* bl = (const float*)d_in[6];
    const float* af = (const float*)d_in[7];
    const float* am = (const float*)d_in[8];
    const float* a0 = (const float*)d_in[9];
    const float* a1 = (const float*)d_in[10];
    const float* a2 = (const float*)d_in[11];
    const float* a3 = (const float*)d_in[12];
    const float* a4 = (const float*)d_in[13];
    const float* a5 = (const float*)d_in[14];
    float* out = (float*)d_out;

    float* ws   = (float*)d_ws;
    float* W1t  = ws;                    // 49152
    float* Wmt  = W1t + 49152;           // 294912
    float* Wlt  = Wmt + 294912;          // 49152
    float* Ta1  = Wlt + 49152;           // 49152
    float* Tam  = Ta1 + 49152;           // 98304
    float* csum = Tam + 98304;           // 15872
    unsigned short* Anth = (unsigned short*)(csum + 15872);  // 62*65536 ushort
    unsigned short* Antl = Anth + (size_t)62 * 65536;        // 62*65536 ushort
    float* B0   = (float*)(Antl + (size_t)62 * 65536);       // 32*1024*256
    float* B1   = B0 + (size_t)32 * N_PTS * M_DIM;           // 32*1024*256

    k_prep<<<2048, 256, 0, stream>>>(wf, wm, wl, af, am, a0, a1, a2, a3, a4,
                                     W1t, Wmt, Wlt, Ta1, Tam, Anth, Antl);
    k_csum_t<<<dim3(62, 64), 256, 0, stream>>>(Anth, Antl, csum);
    k_phase1<<<dim3(32, 32, 2), 256, 0, stream>>>(X, W1t, Wmt, Wlt, b1, bm, bl, Ta1, Tam, B0);

    // HT levels 0..4 (ping-pong B0/B1), normalization fused into epilogue
    k_gemm<0><<<dim3(8, 2, 32), 256, 0, stream>>>(B0, Anth, Antl, csum, B1);
    k_gemm<1><<<dim3(8, 2, 16), 256, 0, stream>>>(B1, Anth + (size_t)32 * 65536,
                                                  Antl + (size_t)32 * 65536, csum + 32 * 256, B0);
    k_gemm<1><<<dim3(8, 2, 8),  256, 0, stream>>>(B0, Anth + (size_t)48 * 65536,
                                                  Antl + (size_t)48 * 65536, csum + 48 * 256, B1);
    k_gemm<1><<<dim3(8, 2, 4),  256, 0, stream>>>(B1, Anth + (size_t)56 * 65536,
                                                  Antl + (size_t)56 * 65536, csum + 56 * 256, B0);
    k_gemm<1><<<dim3(8, 2, 2),  256, 0, stream>>>(B0, Anth + (size_t)60 * 65536,
                                                  Antl + (size_t)60 * 65536, csum + 60 * 256, B1);
    // level 5
    k_l5<<<N_PTS, 256, 0, stream>>>(B1, a5, out);
}

// Round 5
// 206.673 us; speedup vs baseline: 2.4121x; 1.0269x over previous
//
#include <hip/hip_runtime.h>
#include <cstdint>
#include <cstddef>

// Problem constants
#define D_DIM 64
#define M_DIM 256
#define N_PTS 1024

typedef __attribute__((ext_vector_type(4))) float f32x4;
typedef __attribute__((ext_vector_type(8))) short s16x8;

// opaque register pin: prevents the RA from rematerializing/sinking the load
#define KEEP(x) asm volatile("" : "+v"(x))

static __device__ __forceinline__ float sp10f(float x) {
    // softplus(10x)/10, numerically stable, matches jax.nn.softplus
    float t = 10.f * x;
    return 0.1f * (fmaxf(t, 0.f) + log1pf(__expf(-fabsf(t))));
}

// branch-free tanh: 1 - 2/(exp(2x)+1); exact at +-inf (1 / -1), no NaN for finite x
static __device__ __forceinline__ float ftanh(float x) {
    float e = __expf(2.f * x);
    return 1.f - 2.f * __builtin_amdgcn_rcpf(e + 1.f);
}

static __device__ __forceinline__ unsigned short f2bf(float x) {
    unsigned u = __float_as_uint(x);
    u = u + 0x7FFFu + ((u >> 16) & 1u);   // round-to-nearest-even
    return (unsigned short)(u >> 16);
}
static __device__ __forceinline__ float bf2f(unsigned short h) {
    return __uint_as_float(((unsigned)h) << 16);
}

// map global level-group index g (0..61) -> (raw pointer, local g)
static __device__ __forceinline__ const float* map_g(int g, const float* a0, const float* a1,
                                                     const float* a2, const float* a3,
                                                     const float* a4, int& lg) {
    if (g < 32) { lg = g;      return a0; }
    if (g < 48) { lg = g - 32; return a1; }
    if (g < 56) { lg = g - 48; return a2; }
    if (g < 60) { lg = g - 56; return a3; }
    lg = g - 60; return a4;
}

// ---------------- prep: MLP weight transforms (540K elems) ---------------
__global__ void k_prep_w(const float* __restrict__ wf, const float* __restrict__ wm,
                         const float* __restrict__ wl, const float* __restrict__ af,
                         const float* __restrict__ am,
                         float* __restrict__ W1t, float* __restrict__ Wmt,
                         float* __restrict__ Wlt, float* __restrict__ Ta1,
                         float* __restrict__ Tam) {
    const int S0 = 49152, S1 = 294912, S2 = 49152, S3 = 49152, S4 = 98304;
    const int total = S0 + S1 + S2 + S3 + S4;
    for (int i = blockIdx.x * blockDim.x + threadIdx.x; i < total;
         i += gridDim.x * blockDim.x) {
        int j = i;
        if (j < S0) { W1t[j] = sp10f(wf[j]); continue; }
        j -= S0;
        if (j < S1) { Wmt[j] = sp10f(wm[j]); continue; }
        j -= S1;
        if (j < S2) { Wlt[j] = sp10f(wl[j]); continue; }
        j -= S2;
        if (j < S3) { Ta1[j] = tanhf(af[j]); continue; }
        j -= S3;
        Tam[j] = tanhf(am[j]);
    }
}

// ---------------- tiled transpose + sp10 + bf16 hi/lo split --------------
// An_t[g][k][m] = split(sp10(aHT[g][m][k])). 64x64 tiles via LDS.
// grid (4,4,62), block 256.
__global__ __launch_bounds__(256) void k_tr(const float* __restrict__ a0,
                                            const float* __restrict__ a1,
                                            const float* __restrict__ a2,
                                            const float* __restrict__ a3,
                                            const float* __restrict__ a4,
                                            unsigned short* __restrict__ Anth,
                                            unsigned short* __restrict__ Antl) {
    __shared__ float tile[64][65];
    const int g  = blockIdx.z;
    const int m0 = blockIdx.x * 64;
    const int k0 = blockIdx.y * 64;
    int lg;
    const float* A  = map_g(g, a0, a1, a2, a3, a4, lg);
    const float* Ag = A + (size_t)lg * 65536;
    const int t = threadIdx.x;

#pragma unroll
    for (int i = 0; i < 4; i++) {
        const int f   = i * 256 + t;   // 0..1023 float4 slots
        const int row = f >> 4;        // m_local 0..63
        const int c4  = f & 15;        // k float4 col
        float4 v = *(const float4*)(Ag + (size_t)(m0 + row) * 256 + k0 + c4 * 4);
        tile[row][c4 * 4 + 0] = v.x;
        tile[row][c4 * 4 + 1] = v.y;
        tile[row][c4 * 4 + 2] = v.z;
        tile[row][c4 * 4 + 3] = v.w;
    }
    __syncthreads();

#pragma unroll
    for (int i = 0; i < 4; i++) {
        const int f    = i * 256 + t;
        const int krow = f >> 4;       // k_local 0..63
        const int c4   = f & 15;       // m float4 col
        float v0 = sp10f(tile[c4 * 4 + 0][krow]);
        float v1 = sp10f(tile[c4 * 4 + 1][krow]);
        float v2 = sp10f(tile[c4 * 4 + 2][krow]);
        float v3 = sp10f(tile[c4 * 4 + 3][krow]);
        unsigned short h0 = f2bf(v0), h1 = f2bf(v1), h2 = f2bf(v2), h3 = f2bf(v3);
        ushort4 hi, lo;
        hi.x = h0; hi.y = h1; hi.z = h2; hi.w = h3;
        lo.x = f2bf(v0 - bf2f(h0));
        lo.y = f2bf(v1 - bf2f(h1));
        lo.z = f2bf(v2 - bf2f(h2));
        lo.w = f2bf(v3 - bf2f(h3));
        const size_t dst = (size_t)g * 65536 + (size_t)(k0 + krow) * 256 + m0 + c4 * 4;
        *(ushort4*)(Anth + dst) = hi;
        *(ushort4*)(Antl + dst) = lo;
    }
}

// column sums (over m) from transposed hi/lo rows. grid (62,64), 4 waves/blk,
// one k-row per wave, contiguous 8B loads + wave shuffle reduce.
__global__ void k_csum_t(const unsigned short* __restrict__ Anth,
                         const unsigned short* __restrict__ Antl,
                         float* __restrict__ csum) {
    const int g    = blockIdx.x;
    const int w    = threadIdx.x >> 6;
    const int lane = threadIdx.x & 63;
    const int k    = blockIdx.y * 4 + w;
    const size_t base = (size_t)g * 65536 + k * 256 + lane * 4;
    uint2 vh = *(const uint2*)(Anth + base);
    uint2 vl = *(const uint2*)(Antl + base);
    float s = 0.f;
    s += bf2f((unsigned short)(vh.x & 0xFFFFu)) + bf2f((unsigned short)(vh.x >> 16));
    s += bf2f((unsigned short)(vh.y & 0xFFFFu)) + bf2f((unsigned short)(vh.y >> 16));
    s += bf2f((unsigned short)(vl.x & 0xFFFFu)) + bf2f((unsigned short)(vl.x >> 16));
    s += bf2f((unsigned short)(vl.y & 0xFFFFu)) + bf2f((unsigned short)(vl.y >> 16));
    for (int off = 32; off > 0; off >>= 1) s += __shfl_down(s, off);
    if (lane == 0) csum[g * 256 + k] = s;
}

// ---------------- phase 1: one (d,m) chain per thread --------------------
// grid: (j=0..31, nc=0..31, mb=0..1), block 256 = 128 m x 2 e.
// Weights pinned in VGPRs via KEEP() so the RA cannot sink the loads into
// the n-loop (round-4 failure: VGPR=32, all weights reloaded 32x from L2).
__global__ __launch_bounds__(256, 2) void k_phase1(
    const float* __restrict__ X, const float* __restrict__ W1t,
    const float* __restrict__ Wmt, const float* __restrict__ Wlt,
    const float* __restrict__ b1, const float* __restrict__ bm,
    const float* __restrict__ bl, const float* __restrict__ Ta1,
    const float* __restrict__ Tam, float* __restrict__ P0) {
    const int t  = threadIdx.x;
    const int e  = t & 1;
    const int mh = t >> 1;
    const int j  = blockIdx.x;
    const int nc = blockIdx.y;
    const int mb = blockIdx.z;
    const int m  = mb * 128 + mh;
    const int d  = 2 * j + e;
    const int dm = d * M_DIM + m;

    __shared__ float sX[32][2];
    if (t < 64)
        sX[t >> 1][t & 1] = X[(nc * 32 + (t >> 1)) * D_DIM + 2 * j + (t & 1)];

    float W1[3], Wm[2][9], Wl[3], B1[3], Bm[2][3], T1[3], Tm[2][3], Blast;
#pragma unroll
    for (int r = 0; r < 3; r++) {
        W1[r] = W1t[dm * 3 + r];
        B1[r] = b1[dm * 3 + r];
        T1[r] = Ta1[dm * 3 + r];
        Wl[r] = Wlt[dm * 3 + r];
    }
    Blast = bl[dm];
#pragma unroll
    for (int l = 0; l < 2; l++) {
        const size_t b9 = ((size_t)(l * D_DIM + d) * M_DIM + m) * 9;
        const size_t b3 = ((size_t)(l * D_DIM + d) * M_DIM + m) * 3;
#pragma unroll
        for (int q = 0; q < 9; q++) Wm[l][q] = Wmt[b9 + q];
#pragma unroll
        for (int r = 0; r < 3; r++) {
            Bm[l][r] = bm[b3 + r];
            Tm[l][r] = Tam[b3 + r];
        }
    }
    // pin all 43 weights in registers
#pragma unroll
    for (int r = 0; r < 3; r++) {
        KEEP(W1[r]); KEEP(B1[r]); KEEP(T1[r]); KEEP(Wl[r]);
    }
    KEEP(Blast);
#pragma unroll
    for (int l = 0; l < 2; l++) {
#pragma unroll
        for (int q = 0; q < 9; q++) KEEP(Wm[l][q]);
#pragma unroll
        for (int r = 0; r < 3; r++) { KEEP(Bm[l][r]); KEEP(Tm[l][r]); }
    }
    __syncthreads();

    float* outp = P0 + ((size_t)j * N_PTS + nc * 32) * M_DIM + m;
    for (int ni = 0; ni < 32; ni++) {
        const float x = sX[ni][e];
        float phi[3], pd[3];
#pragma unroll
        for (int r = 0; r < 3; r++) {
            float z  = fmaf(x, W1[r], B1[r]);
            float tz = ftanh(z);
            float ta = T1[r];
            pd[r]  = W1[r] * fmaf(ta, fmaf(-tz, tz, 1.f), 1.f);
            phi[r] = z + tz * ta;
        }
#pragma unroll
        for (int l = 0; l < 2; l++) {
            float nphi[3], npd[3];
#pragma unroll
            for (int q = 0; q < 3; q++) {
                float z = Bm[l][q];
                float dp = 0.f;
#pragma unroll
                for (int r = 0; r < 3; r++) {
                    z  = fmaf(phi[r], Wm[l][r * 3 + q], z);
                    dp = fmaf(pd[r],  Wm[l][r * 3 + q], dp);
                }
                float tz = ftanh(z);
                float ta = Tm[l][q];
                nphi[q] = z + tz * ta;
                npd[q]  = dp * fmaf(ta, fmaf(-tz, tz, 1.f), 1.f);
            }
#pragma unroll
            for (int q = 0; q < 3; q++) { phi[q] = nphi[q]; pd[q] = npd[q]; }
        }
        float z = Blast, dp = 0.f;
#pragma unroll
        for (int r = 0; r < 3; r++) {
            z  = fmaf(phi[r], Wl[r], z);
            dp = fmaf(pd[r],  Wl[r], dp);
        }
        float s = __builtin_amdgcn_rcpf(1.f + __expf(-z));
        float prod = dp * s * (1.f - s);
        float other = __shfl_xor(prod, 1);
        if (e == 0) outp[(size_t)ni * M_DIM] = prod * other;
    }
}

// ---------------- phase 2: batched bf16x3 MFMA GEMM ----------------------
// out[g][n][k] = (sum_m Tpair[n][m] * An[g][m][k]) / csum[g][k]
// C = Th*Ah + Th*Al + Tl*Ah  (bf16 hi/lo split, fp32 accumulate)
// block: 256 thr = 4 waves (2x2), tile 128n x 128k, K-step 32 m.
#define LDST 40  // LDS row stride in bf16 elems (32 + 8 pad = 80 B)

template <int PAIRED>
__global__ __launch_bounds__(256, 2) void k_gemm(const float* __restrict__ Tin,
                                                 const unsigned short* __restrict__ Bh,
                                                 const unsigned short* __restrict__ Bl,
                                                 const float* __restrict__ csum,
                                                 float* __restrict__ Tout) {
    __shared__ unsigned short sAh[128 * LDST];
    __shared__ unsigned short sAl[128 * LDST];
    __shared__ unsigned short sBh[128 * LDST];
    __shared__ unsigned short sBl[128 * LDST];

    const int g  = blockIdx.z;
    const int n0 = blockIdx.x * 128;
    const int k0 = blockIdx.y * 128;
    const float* T0 = PAIRED ? Tin + (size_t)(2 * g) * N_PTS * 256
                             : Tin + (size_t)g * N_PTS * 256;
    const float* T1p = PAIRED ? T0 + (size_t)N_PTS * 256 : nullptr;
    const unsigned short* Bhg = Bh + (size_t)g * 65536;
    const unsigned short* Blg = Bl + (size_t)g * 65536;

    const int tid  = threadIdx.x;
    const int lane = tid & 63;
    const int w    = tid >> 6;
    const int wr   = w >> 1;   // n-half of tile
    const int wc   = w & 1;    // k-half of tile
    const int lr   = lane & 15;
    const int lk   = lane >> 4;

    f32x4 acc[4][4];
#pragma unroll
    for (int a = 0; a < 4; a++)
#pragma unroll
        for (int b = 0; b < 4; b++) acc[a][b] = (f32x4){0.f, 0.f, 0.f, 0.f};

    for (int kb = 0; kb < 256; kb += 32) {
        // stage A: 128 n x 32 m fp32 (pair-multiplied) -> hi/lo bf16 LDS
#pragma unroll
        for (int i = 0; i < 4; i++) {
            const int idx = i * 256 + tid;
            const int row = idx >> 3;
            const int m4  = idx & 7;
            float4 v = *(const float4*)(T0 + (size_t)(n0 + row) * 256 + kb + m4 * 4);
            if (PAIRED) {
                float4 u = *(const float4*)(T1p + (size_t)(n0 + row) * 256 + kb + m4 * 4);
                v.x *= u.x; v.y *= u.y; v.z *= u.z; v.w *= u.w;
            }
            unsigned short h0 = f2bf(v.x), h1 = f2bf(v.y), h2 = f2bf(v.z), h3 = f2bf(v.w);
            uint2 hp, lp;
            hp.x = (unsigned)h0 | ((unsigned)h1 << 16);
            hp.y = (unsigned)h2 | ((unsigned)h3 << 16);
            lp.x = (unsigned)f2bf(v.x - bf2f(h0)) | ((unsigned)f2bf(v.y - bf2f(h1)) << 16);
            lp.y = (unsigned)f2bf(v.z - bf2f(h2)) | ((unsigned)f2bf(v.w - bf2f(h3)) << 16);
            *(uint2*)&sAh[row * LDST + m4 * 4] = hp;
            *(uint2*)&sAl[row * LDST + m4 * 4] = lp;
        }
        // stage B: 128 k x 32 m bf16 hi/lo (already split/transposed)
#pragma unroll
        for (int i = 0; i < 2; i++) {
            const int idx  = i * 256 + tid;
            const int krow = idx >> 2;
            const int seg  = idx & 3;
            const size_t src = (size_t)(k0 + krow) * 256 + kb + seg * 8;
            *(uint4*)&sBh[krow * LDST + seg * 8] = *(const uint4*)(Bhg + src);
            *(uint4*)&sBl[krow * LDST + seg * 8] = *(const uint4*)(Blg + src);
        }
        __syncthreads();

        s16x8 ah[4], al[4], bh[4], bl[4];
#pragma unroll
        for (int nt = 0; nt < 4; nt++) {
            const int off = (wr * 64 + nt * 16 + lr) * LDST + lk * 8;
            ah[nt] = *(const s16x8*)&sAh[off];
            al[nt] = *(const s16x8*)&sAl[off];
        }
#pragma unroll
        for (int kt = 0; kt < 4; kt++) {
            const int off = (wc * 64 + kt * 16 + lr) * LDST + lk * 8;
            bh[kt] = *(const s16x8*)&sBh[off];
            bl[kt] = *(const s16x8*)&sBl[off];
        }
#pragma unroll
        for (int nt = 0; nt < 4; nt++)
#pragma unroll
            for (int kt = 0; kt < 4; kt++) {
                acc[nt][kt] = __builtin_amdgcn_mfma_f32_16x16x32_bf16(ah[nt], bh[kt], acc[nt][kt], 0, 0, 0);
                acc[nt][kt] = __builtin_amdgcn_mfma_f32_16x16x32_bf16(ah[nt], bl[kt], acc[nt][kt], 0, 0, 0);
                acc[nt][kt] = __builtin_amdgcn_mfma_f32_16x16x32_bf16(al[nt], bh[kt], acc[nt][kt], 0, 0, 0);
            }
        __syncthreads();
    }

    // epilogue: normalize by column sum, scattered 4B stores (16-lane coalesced)
    float* Og = Tout + (size_t)g * N_PTS * 256;
#pragma unroll
    for (int kt = 0; kt < 4; kt++) {
        const int col = k0 + wc * 64 + kt * 16 + lr;
        const float inv = 1.0f / csum[g * 256 + col];
#pragma unroll
        for (int nt = 0; nt < 4; nt++) {
            const int rbase = n0 + wr * 64 + nt * 16 + lk * 4;
#pragma unroll
            for (int r = 0; r < 4; r++)
                Og[(size_t)(rbase + r) * 256 + col] = acc[nt][kt][r] * inv;
        }
    }
}

// ---------------- level 5: pair-product + normalized dot -----------------
__global__ void k_l5(const float* __restrict__ Tin, const float* __restrict__ a5,
                     float* __restrict__ out) {
    const int n = blockIdx.x;
    const int m = threadIdx.x;
    __shared__ float sv[256], sw[256];
    float w = sp10f(a5[m]);
    float v = Tin[(size_t)n * 256 + m] * Tin[(size_t)(N_PTS + n) * 256 + m] * w;
    sv[m] = v;
    sw[m] = w;
    __syncthreads();
    for (int s = 128; s > 0; s >>= 1) {
        if (m < s) { sv[m] += sv[m + s]; sw[m] += sw[m + s]; }
        __syncthreads();
    }
    if (m == 0) out[n] = sv[0] / sw[0];
}

extern "C" void kernel_launch(void* const* d_in, const int* in_sizes, int n_in,
                              void* d_out, int out_size, void* d_ws, size_t ws_size,
                              hipStream_t stream) {
    const float* X  = (const float*)d_in[0];
    const float* wf = (const float*)d_in[1];
    const float* wm = (const float*)d_in[2];
    const float* wl = (const float*)d_in[3];
    const float* b1 = (const float*)d_in[4];
    const float* bm = (const float*)d_in[5];
    const float* bl = (const float*)d_in[6];
    const float* af = (const float*)d_in[7];
    const float* am = (const float*)d_in[8];
    const float* a0 = (const float*)d_in[9];
    const float* a1 = (const float*)d_in[10];
    const float* a2 = (const float*)d_in[11];
    const float* a3 = (const float*)d_in[12];
    const float* a4 = (const float*)d_in[13];
    const float* a5 = (const float*)d_in[14];
    float* out = (float*)d_out;

    float* ws   = (float*)d_ws;
    float* W1t  = ws;                    // 49152
    float* Wmt  = W1t + 49152;           // 294912
    float* Wlt  = Wmt + 294912;          // 49152
    float* Ta1  = Wlt + 49152;           // 49152
    float* Tam  = Ta1 + 49152;           // 98304
    float* csum = Tam + 98304;           // 15872
    unsigned short* Anth = (unsigned short*)(csum + 15872);  // 62*65536 ushort
    unsigned short* Antl = Anth + (size_t)62 * 65536;        // 62*65536 ushort
    float* B0   = (float*)(Antl + (size_t)62 * 65536);       // 32*1024*256
    float* B1   = B0 + (size_t)32 * N_PTS * M_DIM;           // 32*1024*256

    k_prep_w<<<512, 256, 0, stream>>>(wf, wm, wl, af, am, W1t, Wmt, Wlt, Ta1, Tam);
    k_tr<<<dim3(4, 4, 62), 256, 0, stream>>>(a0, a1, a2, a3, a4, Anth, Antl);
    k_csum_t<<<dim3(62, 64), 256, 0, stream>>>(Anth, Antl, csum);
    k_phase1<<<dim3(32, 32, 2), 256, 0, stream>>>(X, W1t, Wmt, Wlt, b1, bm, bl, Ta1, Tam, B0);

    // HT levels 0..4 (ping-pong B0/B1), normalization fused into epilogue
    k_gemm<0><<<dim3(8, 2, 32), 256, 0, stream>>>(B0, Anth, Antl, csum, B1);
    k_gemm<1><<<dim3(8, 2, 16), 256, 0, stream>>>(B1, Anth + (size_t)32 * 65536,
                                                  Antl + (size_t)32 * 65536, csum + 32 * 256, B0);
    k_gemm<1><<<dim3(8, 2, 8),  256, 0, stream>>>(B0, Anth + (size_t)48 * 65536,
                                                  Antl + (size_t)48 * 65536, csum + 48 * 256, B1);
    k_gemm<1><<<dim3(8, 2, 4),  256, 0, stream>>>(B1, Anth + (size_t)56 * 65536,
                                                  Antl + (size_t)56 * 65536, csum + 56 * 256, B0);
    k_gemm<1><<<dim3(8, 2, 2),  256, 0, stream>>>(B0, Anth + (size_t)60 * 65536,
                                                  Antl + (size_t)60 * 65536, csum + 60 * 256, B1);
    // level 5
    k_l5<<<N_PTS, 256, 0, stream>>>(B1, a5, out);
}